// Round 1
// baseline (3451.513 us; speedup 1.0000x reference)
//
#include <hip/hip_runtime.h>

#define HH 128
#define WW 128
#define NIMG 32
#define CH 16
#define TILE 16
#define LW 20            // TILE + 4 (halo of 2)
#define NUM_ITER 30
#define THR 0.1f

// ---------------- init: build 16-ch cell state from 10-ch input ----------------
__global__ __launch_bounds__(256) void init_kernel(const float* __restrict__ inp,
                                                   float* __restrict__ cell) {
    int i = blockIdx.x * 256 + threadIdx.x;       // over NIMG*CH*H*W
    if (i >= NIMG * CH * HH * WW) return;
    int hw = i % (HH * WW);
    int c  = (i / (HH * WW)) % CH;
    int n  = i / (CH * HH * WW);
    float v;
    if (c == 0)       v = 1.0f - inp[(n * 10 + 0) * HH * WW + hw];
    else if (c <= 10) v = inp[(n * 10 + (c - 1)) * HH * WW + hw];
    else              v = 0.0f;
    cell[i] = v;
}

// ---------------- w2 [16,48] -> w2t [48,16] so rows are contiguous -------------
__global__ void transpose_w2(const float* __restrict__ w2, float* __restrict__ w2t) {
    int i = threadIdx.x;
    if (i < 768) {
        int o = i / 16, k = i % 16;
        w2t[o * 16 + k] = w2[k * 48 + o];
    }
}

// perception: p[0..15]=center, p[16..31]=sobel-x, p[32..47]=sobel-y
__device__ __forceinline__ void perception_at(const float* cs, int base, float* p) {
#pragma unroll
    for (int c = 0; c < CH; ++c) {
        const float* cc = cs + c * (LW * LW);
        float c00 = cc[base - LW - 1], c01 = cc[base - LW], c02 = cc[base - LW + 1];
        float c10 = cc[base - 1],      c11 = cc[base],      c12 = cc[base + 1];
        float c20 = cc[base + LW - 1], c21 = cc[base + LW], c22 = cc[base + LW + 1];
        p[c]      = c11;
        p[16 + c] = (c02 - c00 + 2.0f * (c12 - c10) + c22 - c20) * 0.125f;
        p[32 + c] = (c20 - c00 + 2.0f * (c21 - c01) + c22 - c02) * 0.125f;
    }
}

__device__ __forceinline__ float dot48(const float* __restrict__ w, const float* p) {
    float a0 = 0.f, a1 = 0.f, a2 = 0.f, a3 = 0.f;
#pragma unroll
    for (int c = 0; c < 48; c += 4) {
        a0 = fmaf(w[c + 0], p[c + 0], a0);
        a1 = fmaf(w[c + 1], p[c + 1], a1);
        a2 = fmaf(w[c + 2], p[c + 2], a2);
        a3 = fmaf(w[c + 3], p[c + 3], a3);
    }
    return (a0 + a1) + (a2 + a3);
}

// ---------------- one fused CA step ----------------
__global__ __launch_bounds__(256) void step_kernel(
    const float* __restrict__ cin, float* __restrict__ cout,
    const float* __restrict__ w1, const float* __restrict__ w2t,
    float* __restrict__ fout /* non-null on last iter: write channels 1..10 */) {

    __shared__ float cs[CH * LW * LW];   // 16 x 20 x 20 cell tile (halo 2), zero-filled OOB
    __shared__ float cur0s[18 * 20];     // cur channel-0 for inner+halo1 (18x18, stride 20)

    const int tid = threadIdx.x;
    const int tx = tid & 15, ty = tid >> 4;
    const int bx = blockIdx.x * TILE, by = blockIdx.y * TILE;
    const int n = blockIdx.z;
    const float* cbase = cin + (size_t)n * CH * HH * WW;

    // ---- stage cell tile to LDS (zero-fill out of image: matches conv zero-pad
    // and maxpool -inf pad since 0 < 0.1 threshold) ----
    for (int i = tid; i < CH * LW * LW; i += 256) {
        int c = i / (LW * LW);
        int r = i % (LW * LW);
        int ly = r / LW, lx = r % LW;
        int gy = by + ly - 2, gx = bx + lx - 2;
        float v = 0.0f;
        if (gx >= 0 && gx < WW && gy >= 0 && gy < HH)
            v = cbase[c * HH * WW + gy * WW + gx];
        cs[i] = v;
    }
    __syncthreads();

    // ---- primary (inner) pixel ----
    const int base = (ty + 2) * LW + (tx + 2);

    // pre life mask: 3x3 max of channel 0 around this pixel
    float pm = -1e30f;
#pragma unroll
    for (int dy = -1; dy <= 1; ++dy)
#pragma unroll
        for (int dx = -1; dx <= 1; ++dx)
            pm = fmaxf(pm, cs[base + dy * LW + dx]);
    const bool pre = pm > THR;

    float p[48];
    perception_at(cs, base, p);

    float cur[16];
#pragma unroll
    for (int k = 0; k < 16; ++k) cur[k] = p[k];   // residual = cell center

    for (int o = 0; o < 48; ++o) {
        float hv = fmaxf(dot48(w1 + o * 48, p), 0.0f);
#pragma unroll
        for (int k = 0; k < 16; ++k) cur[k] = fmaf(w2t[o * 16 + k], hv, cur[k]);
    }
    cur0s[(ty + 1) * 20 + (tx + 1)] = cur[0];

    // ---- secondary: halo ring of the 18x18 cur0 region (cur[0] only) ----
    if (tid < 68) {
        int hx, hy;
        if (tid < 18)      { hy = -1; hx = tid - 1; }
        else if (tid < 36) { hy = 16; hx = tid - 19; }
        else if (tid < 52) { hx = -1; hy = tid - 36; }
        else               { hx = 16; hy = tid - 52; }
        const int hb = (hy + 2) * LW + (hx + 2);
        float ph[48];
        perception_at(cs, hb, ph);
        float c0 = ph[0];
        for (int o = 0; o < 48; ++o) {
            float hv = fmaxf(dot48(w1 + o * 48, ph), 0.0f);
            c0 = fmaf(w2t[o * 16 + 0], hv, c0);
        }
        cur0s[(hy + 1) * 20 + (hx + 1)] = c0;
    }
    __syncthreads();

    // ---- post life mask on cur0, gate, write ----
    float qm = -1e30f;
    const int cb = (ty + 1) * 20 + (tx + 1);
#pragma unroll
    for (int dy = -1; dy <= 1; ++dy)
#pragma unroll
        for (int dx = -1; dx <= 1; ++dx)
            qm = fmaxf(qm, cur0s[cb + dy * 20 + dx]);
    const bool alive = pre && (qm > THR);

    float* obase = cout + (size_t)n * CH * HH * WW + (by + ty) * WW + (bx + tx);
#pragma unroll
    for (int k = 0; k < 16; ++k)
        obase[k * HH * WW] = alive ? cur[k] : 0.0f;

    if (fout) {
        float* fbase = fout + (size_t)n * 10 * HH * WW + (by + ty) * WW + (bx + tx);
#pragma unroll
        for (int k = 1; k < 11; ++k)
            fbase[(k - 1) * HH * WW] = alive ? cur[k] : 0.0f;
    }
}

extern "C" void kernel_launch(void* const* d_in, const int* in_sizes, int n_in,
                              void* d_out, int out_size, void* d_ws, size_t ws_size,
                              hipStream_t stream) {
    const float* inp = (const float*)d_in[0];
    const float* w1  = (const float*)d_in[1];
    const float* w2  = (const float*)d_in[2];
    float* out = (float*)d_out;

    const size_t state_elems = (size_t)NIMG * CH * HH * WW;   // 8,388,608
    float* bufA = (float*)d_ws;
    float* bufB = bufA + state_elems;
    float* w2t  = bufB + state_elems;

    int total = (int)state_elems;
    init_kernel<<<(total + 255) / 256, 256, 0, stream>>>(inp, bufA);
    transpose_w2<<<1, 768, 0, stream>>>(w2, w2t);

    dim3 grid(WW / TILE, HH / TILE, NIMG);
    for (int it = 0; it < NUM_ITER; ++it) {
        float* src = (it & 1) ? bufB : bufA;
        float* dst = (it & 1) ? bufA : bufB;
        step_kernel<<<grid, 256, 0, stream>>>(src, dst, w1, w2t,
                                              (it == NUM_ITER - 1) ? out : nullptr);
    }
}

// Round 3
// 2616.364 us; speedup vs baseline: 1.3192x; 1.3192x over previous
//
#include <hip/hip_runtime.h>
#include <stdint.h>

#define HH 128
#define WW 128
#define NIMG 32
#define CH 16
#define TILE 16
#define LW 20            // 16 + 2*2 halo
#define NUM_ITER 30
#define THR 0.1f
#define HWSZ (HH * WW)

// ---------------- init: build 16-ch cell state from 10-ch input ----------------
__global__ __launch_bounds__(256) void init_kernel(const float* __restrict__ inp,
                                                   float* __restrict__ cell) {
    int i = blockIdx.x * 256 + threadIdx.x;
    if (i >= NIMG * CH * HWSZ) return;
    int hw = i % HWSZ;
    int c  = (i / HWSZ) % CH;
    int n  = i / (CH * HWSZ);
    float v;
    if (c == 0)       v = 1.0f - inp[(n * 10 + 0) * HWSZ + hw];
    else if (c <= 10) v = inp[(n * 10 + (c - 1)) * HWSZ + hw];
    else              v = 0.0f;
    cell[i] = v;
}

// ---------------- w2 [16,48] -> w2t [48,16] -------------
__global__ void transpose_w2(const float* __restrict__ w2, float* __restrict__ w2t) {
    int i = threadIdx.x;
    if (i < 768) {
        int o = i / 16, k = i % 16;
        w2t[o * 16 + k] = w2[k * 48 + o];
    }
}

// perception: p[0..15]=center, p[16..31]=sobel-x, p[32..47]=sobel-y
__device__ __forceinline__ void perception_at(const float* cs, int base, float* p) {
#pragma unroll
    for (int c = 0; c < CH; ++c) {
        const float* cc = cs + c * (LW * LW);
        float c00 = cc[base - LW - 1], c01 = cc[base - LW], c02 = cc[base - LW + 1];
        float c10 = cc[base - 1],      c11 = cc[base],      c12 = cc[base + 1];
        float c20 = cc[base + LW - 1], c21 = cc[base + LW], c22 = cc[base + LW + 1];
        p[c]      = c11;
        p[16 + c] = (c02 - c00 + 2.0f * (c12 - c10) + c22 - c20) * 0.125f;
        p[32 + c] = (c20 - c00 + 2.0f * (c21 - c01) + c22 - c02) * 0.125f;
    }
}

__device__ __forceinline__ float dot48(const float* __restrict__ w, const float* p) {
    float a0 = 0.f, a1 = 0.f, a2 = 0.f, a3 = 0.f;
#pragma unroll
    for (int c = 0; c < 48; c += 4) {
        a0 = fmaf(w[c + 0], p[c + 0], a0);
        a1 = fmaf(w[c + 1], p[c + 1], a1);
        a2 = fmaf(w[c + 2], p[c + 2], a2);
        a3 = fmaf(w[c + 3], p[c + 3], a3);
    }
    return (a0 + a1) + (a2 + a3);
}

// ---------------- one fused CA step ----------------
// State carried between iterations: ungated cur (16ch) + pre-mask bits.
// Reconstruct gated cell(i-1) = cur(i-1) * (pre(i-1) & post(i-1)) in LDS
// (post computed locally from ch0 halo), emit pre(i) bits, compute ungated
// cur(i) for the inner 16x16 only. No redundant matmul work.
__global__ __launch_bounds__(256) void step_kernel(
    const float* __restrict__ cin, float* __restrict__ cout,
    const uint8_t* __restrict__ pre_in, uint8_t* __restrict__ pre_out,
    const float* __restrict__ w1, const float* __restrict__ w2t,
    int gate) {

    __shared__ float cs[CH * LW * LW];   // 16 x 20 x 20, zero-filled OOB
    __shared__ float gm[324];            // gate mask over the 18x18 region

    const int tid = threadIdx.x;
    const int tx = tid & 15, ty = tid >> 4;
    const int bx = blockIdx.x * TILE, by = blockIdx.y * TILE;
    const int n = blockIdx.z;
    const float* cbase = cin + (size_t)n * CH * HWSZ;

    // ---- stage cur(i-1) tile (halo 2) to LDS; zero-fill outside image ----
    for (int i = tid; i < CH * LW * LW; i += 256) {
        int c = i / (LW * LW);
        int r = i % (LW * LW);
        int ly = r / LW, lx = r % LW;
        int gy = by + ly - 2, gx = bx + lx - 2;
        float v = 0.0f;
        if ((unsigned)gy < HH && (unsigned)gx < WW)
            v = cbase[c * HWSZ + gy * WW + gx];
        cs[i] = v;
    }
    __syncthreads();

    // ---- gate mask for the 18x18 (halo-1) region ----
    // NOTE: strided — 324 items > 256 threads (R2 bug: `if (tid<324)` left
    // gm[256..323] uninitialized -> state explosion).
    for (int i = tid; i < 324; i += 256) {
        int ly = i / 18, lx = i % 18;
        int y = ly + 1, x = lx + 1;         // coords in 20x20 buffer
        float pm = -1e30f;
#pragma unroll
        for (int dy = -1; dy <= 1; ++dy)
#pragma unroll
            for (int dx = -1; dx <= 1; ++dx)
                pm = fmaxf(pm, cs[(y + dy) * LW + (x + dx)]);   // ch0 post-mask
        float mval = 1.0f;
        if (gate) {
            int gy = by + ly - 1, gx = bx + lx - 1;
            int pv = 0;
            if ((unsigned)gy < HH && (unsigned)gx < WW)
                pv = pre_in[(size_t)n * HWSZ + gy * WW + gx];
            mval = (pv && pm > THR) ? 1.0f : 0.0f;
        }
        gm[i] = mval;
    }
    __syncthreads();

    // ---- apply gate in LDS: cell(i-1) = cur(i-1) * mask over 18x18 x 16ch ----
    if (gate) {
        for (int i = tid; i < CH * 324; i += 256) {
            int c = i / 324, j = i % 324;
            int ly = j / 18, lx = j % 18;
            cs[c * (LW * LW) + (ly + 1) * LW + (lx + 1)] *= gm[j];
        }
    }
    __syncthreads();

    // ---- pre(i) = life_mask(cell(i-1)) for inner pixel; store bits ----
    const int base = (ty + 2) * LW + (tx + 2);
    float pm = -1e30f;
#pragma unroll
    for (int dy = -1; dy <= 1; ++dy)
#pragma unroll
        for (int dx = -1; dx <= 1; ++dx)
            pm = fmaxf(pm, cs[base + dy * LW + dx]);
    pre_out[(size_t)n * HWSZ + (size_t)(by + ty) * WW + (bx + tx)] = (pm > THR) ? 1 : 0;

    // ---- perception + matmuls (inner pixels only, uniform across block) ----
    float p[48];
    perception_at(cs, base, p);

    float cur[16];
#pragma unroll
    for (int k = 0; k < 16; ++k) cur[k] = p[k];   // residual

#pragma unroll 4
    for (int o = 0; o < 48; ++o) {
        float hv = fmaxf(dot48(w1 + o * 48, p), 0.0f);
#pragma unroll
        for (int k = 0; k < 16; ++k) cur[k] = fmaf(w2t[o * 16 + k], hv, cur[k]);
    }

    float* obase = cout + (size_t)n * CH * HWSZ + (size_t)(by + ty) * WW + (bx + tx);
#pragma unroll
    for (int k = 0; k < 16; ++k)
        obase[k * HWSZ] = cur[k];
}

// ---------------- final: apply gate(30), emit channels 1..10 ----------------
__global__ __launch_bounds__(256) void final_kernel(
    const float* __restrict__ cur, const uint8_t* __restrict__ pre,
    float* __restrict__ out) {
    int i = blockIdx.x * 256 + threadIdx.x;        // over NIMG*H*W
    if (i >= NIMG * HWSZ) return;
    int x = i % WW, y = (i / WW) % HH, n = i / HWSZ;
    const float* c0 = cur + (size_t)n * CH * HWSZ;
    float pm = -1e30f;
    for (int dy = -1; dy <= 1; ++dy) {
        int yy = y + dy;
        if ((unsigned)yy >= HH) continue;
        for (int dx = -1; dx <= 1; ++dx) {
            int xx = x + dx;
            if ((unsigned)xx >= WW) continue;
            pm = fmaxf(pm, c0[yy * WW + xx]);
        }
    }
    const bool alive = pre[i] && (pm > THR);
    float* ob = out + (size_t)n * 10 * HWSZ + y * WW + x;
#pragma unroll
    for (int k = 1; k <= 10; ++k)
        ob[(k - 1) * HWSZ] = alive ? c0[k * HWSZ + y * WW + x] : 0.0f;
}

extern "C" void kernel_launch(void* const* d_in, const int* in_sizes, int n_in,
                              void* d_out, int out_size, void* d_ws, size_t ws_size,
                              hipStream_t stream) {
    const float* inp = (const float*)d_in[0];
    const float* w1  = (const float*)d_in[1];
    const float* w2  = (const float*)d_in[2];
    float* out = (float*)d_out;

    const size_t SE = (size_t)NIMG * CH * HWSZ;    // 8,388,608 floats
    float* bufA = (float*)d_ws;
    float* bufB = bufA + SE;
    float* w2t  = bufB + SE;
    uint8_t* bitsA = (uint8_t*)(w2t + 768);
    uint8_t* bitsB = bitsA + (size_t)NIMG * HWSZ;

    init_kernel<<<((int)SE + 255) / 256, 256, 0, stream>>>(inp, bufA);
    transpose_w2<<<1, 768, 0, stream>>>(w2, w2t);

    dim3 grid(WW / TILE, HH / TILE, NIMG);
    float* src = bufA;
    float* dst = bufB;
    uint8_t* pin = bitsB;   // unused on first iter (gate=0)
    uint8_t* pout = bitsA;
    for (int it = 0; it < NUM_ITER; ++it) {
        step_kernel<<<grid, 256, 0, stream>>>(src, dst, pin, pout, w1, w2t,
                                              it == 0 ? 0 : 1);
        float* t = src; src = dst; dst = t;
        uint8_t* tb = pin; pin = pout; pout = tb;
    }
    // after loop: src = cur(30), pin = pre(30) bits
    final_kernel<<<(NIMG * HWSZ + 255) / 256, 256, 0, stream>>>(src, pin, out);
}

// Round 4
// 2220.303 us; speedup vs baseline: 1.5545x; 1.1784x over previous
//
#include <hip/hip_runtime.h>
#include <stdint.h>

#define HH 128
#define WW 128
#define NIMG 32
#define CH 16
#define TILE 16
#define LW 20            // 16 + 2*2 halo
#define LA (LW * LW)     // 400 floats per channel plane
#define NUM_ITER 30
#define THR 0.1f
#define HWSZ (HH * WW)

// ---------------- init: build 16-ch cell state from 10-ch input ----------------
__global__ __launch_bounds__(256) void init_kernel(const float* __restrict__ inp,
                                                   float* __restrict__ cell) {
    int i = blockIdx.x * 256 + threadIdx.x;
    if (i >= NIMG * CH * HWSZ) return;
    int hw = i % HWSZ;
    int c  = (i / HWSZ) % CH;
    int n  = i / (CH * HWSZ);
    float v;
    if (c == 0)       v = 1.0f - inp[(n * 10 + 0) * HWSZ + hw];
    else if (c <= 10) v = inp[(n * 10 + (c - 1)) * HWSZ + hw];
    else              v = 0.0f;
    cell[i] = v;
}

// ---------------- w2 [16,48] -> w2t [48,16] -------------
__global__ void transpose_w2(const float* __restrict__ w2, float* __restrict__ w2t) {
    int i = threadIdx.x;
    if (i < 768) {
        int o = i / 16, k = i % 16;
        w2t[o * 16 + k] = w2[k * 48 + o];
    }
}

// perception: p[0..15]=center, p[16..31]=sobel-x, p[32..47]=sobel-y
__device__ __forceinline__ void perception_at(const float* cs, int base, float* p) {
#pragma unroll
    for (int c = 0; c < CH; ++c) {
        const float* cc = cs + c * LA;
        float c00 = cc[base - LW - 1], c01 = cc[base - LW], c02 = cc[base - LW + 1];
        float c10 = cc[base - 1],      c11 = cc[base],      c12 = cc[base + 1];
        float c20 = cc[base + LW - 1], c21 = cc[base + LW], c22 = cc[base + LW + 1];
        p[c]      = c11;
        p[16 + c] = (c02 - c00 + 2.0f * (c12 - c10) + c22 - c20) * 0.125f;
        p[32 + c] = (c20 - c00 + 2.0f * (c21 - c01) + c22 - c02) * 0.125f;
    }
}

__device__ __forceinline__ float dot48(const float* __restrict__ w, const float* p) {
    float a0 = 0.f, a1 = 0.f, a2 = 0.f, a3 = 0.f;
#pragma unroll
    for (int c = 0; c < 48; c += 4) {
        a0 = fmaf(w[c + 0], p[c + 0], a0);
        a1 = fmaf(w[c + 1], p[c + 1], a1);
        a2 = fmaf(w[c + 2], p[c + 2], a2);
        a3 = fmaf(w[c + 3], p[c + 3], a3);
    }
    return (a0 + a1) + (a2 + a3);
}

// ---------------- one fused CA step ----------------
// Carried state: ungated cur (16ch) + pre-mask bits.
// Phases: A) stage raw ch0 20x20  B) gate mask gm over 18x18 (post from ch0,
// pre bits from global)  C) gate ch0 in LDS + stage ch1..15 *only* for the
// 18x18 live region with gate folded into the load  D) pre(i) bits,
// perception, matmuls, store ungated cur(i).
// launch_bounds(256,3): VGPR cap ~170 so p[48]+cur[16] stay in real VGPRs
// (R3 showed VGPR_Count=60 -> AGPR spill shuffling of p[], ~2x issue volume).
__global__ __launch_bounds__(256, 3) void step_kernel(
    const float* __restrict__ cin, float* __restrict__ cout,
    const uint8_t* __restrict__ pre_in, uint8_t* __restrict__ pre_out,
    const float* __restrict__ w1, const float* __restrict__ w2t,
    int gate) {

    __shared__ float cs[CH * LA];   // 16 x 20 x 20 (ch1..15: only 18x18 valid)
    __shared__ float gm[324];       // gate mask over the 18x18 region

    const int tid = threadIdx.x;
    const int tx = tid & 15, ty = tid >> 4;
    const int bx = blockIdx.x * TILE, by = blockIdx.y * TILE;
    const int n = blockIdx.z;
    const float* cbase = cin + (size_t)n * CH * HWSZ;
    const uint8_t* pbase = pre_in + (size_t)n * HWSZ;

    // ---- hoisted coords: full 20x20 positions (ch0), two per thread ----
    const int lyA = tid / 20, lxA = tid % 20;
    const int gyA = by + lyA - 2, gxA = bx + lxA - 2;
    const bool okA = ((unsigned)gyA < HH) && ((unsigned)gxA < WW);
    const int offA = gyA * WW + gxA;

    const int rB = tid + 256;                  // valid when tid < 144
    const int lyB = rB / 20, lxB = rB % 20;
    const int gyB = by + lyB - 2, gxB = bx + lxB - 2;
    const bool okB = ((unsigned)gyB < HH) && ((unsigned)gxB < WW);
    const int offB = gyB * WW + gxB;

    // ---- hoisted coords: 18x18 region positions, two per thread ----
    const int j0 = tid;                        // always < 324
    const int jy0 = j0 / 18, jx0 = j0 % 18;
    const int gy0 = by + jy0 - 1, gx0 = bx + jx0 - 1;
    const bool ok0 = ((unsigned)gy0 < HH) && ((unsigned)gx0 < WW);
    const int goff0 = gy0 * WW + gx0;
    const int lpos0 = (jy0 + 1) * LW + (jx0 + 1);

    const int j1 = tid + 256;                  // valid when tid < 68
    const int jy1 = j1 / 18, jx1 = j1 % 18;
    const int gy1 = by + jy1 - 1, gx1 = bx + jx1 - 1;
    const bool ok1 = ((unsigned)gy1 < HH) && ((unsigned)gx1 < WW);
    const int goff1 = gy1 * WW + gx1;
    const int lpos1 = (jy1 + 1) * LW + (jx1 + 1);

    // ---- A: stage raw ch0 (full 20x20, zero-fill OOB) ----
    cs[tid] = okA ? cbase[offA] : 0.0f;
    if (tid < 144) cs[rB] = okB ? cbase[offB] : 0.0f;
    __syncthreads();

    // ---- B: gate mask gm over 18x18 (post-mask of cur(i-1) ch0 & pre bits) ----
    {
        float pm = -1e30f;
#pragma unroll
        for (int dy = -1; dy <= 1; ++dy)
#pragma unroll
            for (int dx = -1; dx <= 1; ++dx)
                pm = fmaxf(pm, cs[lpos0 + dy * LW + dx]);
        float mval = 1.0f;
        if (gate) {
            int pv = ok0 ? pbase[goff0] : 0;
            mval = (pv && pm > THR) ? 1.0f : 0.0f;
        }
        gm[j0] = mval;
    }
    if (tid < 68) {
        float pm = -1e30f;
#pragma unroll
        for (int dy = -1; dy <= 1; ++dy)
#pragma unroll
            for (int dx = -1; dx <= 1; ++dx)
                pm = fmaxf(pm, cs[lpos1 + dy * LW + dx]);
        float mval = 1.0f;
        if (gate) {
            int pv = ok1 ? pbase[goff1] : 0;
            mval = (pv && pm > THR) ? 1.0f : 0.0f;
        }
        gm[j1] = mval;
    }
    __syncthreads();

    // ---- C: gate ch0 in LDS; stage ch1..15 (18x18 only) with gate folded in ----
    {
        const float g = gm[j0];
        cs[lpos0] *= g;
        const float* gp = cbase + goff0;
#pragma unroll
        for (int c = 1; c < CH; ++c)
            cs[c * LA + lpos0] = (ok0 ? gp[c * HWSZ] : 0.0f) * g;
    }
    if (tid < 68) {
        const float g = gm[j1];
        cs[lpos1] *= g;
        const float* gp = cbase + goff1;
#pragma unroll
        for (int c = 1; c < CH; ++c)
            cs[c * LA + lpos1] = (ok1 ? gp[c * HWSZ] : 0.0f) * g;
    }
    __syncthreads();

    // ---- D: pre(i) bits, perception, matmuls (inner 16x16 only) ----
    const int base = (ty + 2) * LW + (tx + 2);
    float pm = -1e30f;
#pragma unroll
    for (int dy = -1; dy <= 1; ++dy)
#pragma unroll
        for (int dx = -1; dx <= 1; ++dx)
            pm = fmaxf(pm, cs[base + dy * LW + dx]);
    pre_out[(size_t)n * HWSZ + (size_t)(by + ty) * WW + (bx + tx)] = (pm > THR) ? 1 : 0;

    float p[48];
    perception_at(cs, base, p);

    float cur[16];
#pragma unroll
    for (int k = 0; k < 16; ++k) cur[k] = p[k];   // residual

#pragma unroll 4
    for (int o = 0; o < 48; ++o) {
        float hv = fmaxf(dot48(w1 + o * 48, p), 0.0f);
#pragma unroll
        for (int k = 0; k < 16; ++k) cur[k] = fmaf(w2t[o * 16 + k], hv, cur[k]);
    }

    float* obase = cout + (size_t)n * CH * HWSZ + (size_t)(by + ty) * WW + (bx + tx);
#pragma unroll
    for (int k = 0; k < 16; ++k)
        obase[k * HWSZ] = cur[k];
}

// ---------------- final: apply gate(30), emit channels 1..10 ----------------
__global__ __launch_bounds__(256) void final_kernel(
    const float* __restrict__ cur, const uint8_t* __restrict__ pre,
    float* __restrict__ out) {
    int i = blockIdx.x * 256 + threadIdx.x;        // over NIMG*H*W
    if (i >= NIMG * HWSZ) return;
    int x = i % WW, y = (i / WW) % HH, n = i / HWSZ;
    const float* c0 = cur + (size_t)n * CH * HWSZ;
    float pm = -1e30f;
    for (int dy = -1; dy <= 1; ++dy) {
        int yy = y + dy;
        if ((unsigned)yy >= HH) continue;
        for (int dx = -1; dx <= 1; ++dx) {
            int xx = x + dx;
            if ((unsigned)xx >= WW) continue;
            pm = fmaxf(pm, c0[yy * WW + xx]);
        }
    }
    const bool alive = pre[i] && (pm > THR);
    float* ob = out + (size_t)n * 10 * HWSZ + y * WW + x;
#pragma unroll
    for (int k = 1; k <= 10; ++k)
        ob[(k - 1) * HWSZ] = alive ? c0[k * HWSZ + y * WW + x] : 0.0f;
}

extern "C" void kernel_launch(void* const* d_in, const int* in_sizes, int n_in,
                              void* d_out, int out_size, void* d_ws, size_t ws_size,
                              hipStream_t stream) {
    const float* inp = (const float*)d_in[0];
    const float* w1  = (const float*)d_in[1];
    const float* w2  = (const float*)d_in[2];
    float* out = (float*)d_out;

    const size_t SE = (size_t)NIMG * CH * HWSZ;    // 8,388,608 floats
    float* bufA = (float*)d_ws;
    float* bufB = bufA + SE;
    float* w2t  = bufB + SE;
    uint8_t* bitsA = (uint8_t*)(w2t + 768);
    uint8_t* bitsB = bitsA + (size_t)NIMG * HWSZ;

    init_kernel<<<((int)SE + 255) / 256, 256, 0, stream>>>(inp, bufA);
    transpose_w2<<<1, 768, 0, stream>>>(w2, w2t);

    dim3 grid(WW / TILE, HH / TILE, NIMG);
    float* src = bufA;
    float* dst = bufB;
    uint8_t* pin = bitsB;   // unused on first iter (gate=0)
    uint8_t* pout = bitsA;
    for (int it = 0; it < NUM_ITER; ++it) {
        step_kernel<<<grid, 256, 0, stream>>>(src, dst, pin, pout, w1, w2t,
                                              it == 0 ? 0 : 1);
        float* t = src; src = dst; dst = t;
        uint8_t* tb = pin; pin = pout; pout = tb;
    }
    // after loop: src = cur(30), pin = pre(30) bits
    final_kernel<<<(NIMG * HWSZ + 255) / 256, 256, 0, stream>>>(src, pin, out);
}